// Round 1
// baseline (1411.988 us; speedup 1.0000x reference)
//
#include <hip/hip_runtime.h>
#include <hip/hip_bf16.h>
#include <stdint.h>

#define NTOK 8
#define NH   8
#define DH   16
#define CD   128
#define LP   54   // 6*9 positions

__device__ __forceinline__ float ldT(const __hip_bfloat16* p, int i){ return __bfloat162float(p[i]); }
__device__ __forceinline__ float ldT(const float* p, int i){ return p[i]; }

__device__ __forceinline__ float gelu_exact(float z){
  return 0.5f * z * (1.0f + erff(z * 0.70710678118654752440f));
}

// region of token t: t0->r0, t1->r1, t>=2 -> t-2
__device__ __forceinline__ int reg_of(int t){ return (t < 2) ? t : (t - 2); }
// position l of region r, local index ll (0..8), grid 6x9
__device__ __forceinline__ int pos_of(int r, int ll){
  return ((r / 3) * 3 + ll / 3) * 9 + (r % 3) * 3 + (ll % 3);
}

// ---------------- dtype detect: ln1_g is all ones ----------------
__global__ void detect_kernel(const unsigned int* g, int* flag){
  // fp32 1.0 -> 0x3F800000 ; two packed bf16 1.0 -> 0x3F803F80
  *flag = (*g == 0x3F800000u) ? 0 : 1;   // 0 = fp32, 1 = bf16
}

// ---------------- stage A: q = LN(query)@Wq+bq ; A[t,h,c] = 0.25*sum_d q[t,h16+d]*Wk[c,h16+d]
template<typename T, int FV>
__global__ __launch_bounds__(256) void stageA_kernel(const int* flag,
    const T* __restrict__ query, const T* __restrict__ g1, const T* __restrict__ b1,
    const T* __restrict__ Wq, const T* __restrict__ bq, const T* __restrict__ Wk,
    float* __restrict__ Af, __hip_bfloat16* __restrict__ Ab)
{
  if (*flag != FV) return;
  __shared__ float qn[NTOK][CD];
  __shared__ float qq[NTOK][CD];
  const int tid = threadIdx.x;
  const int t = tid >> 5, lane = tid & 31;
  // LayerNorm of query token t (group of 32 lanes per token)
  float xv[4]; float s = 0.f;
  for (int k = 0; k < 4; k++){ xv[k] = ldT(query, t*CD + lane + 32*k); s += xv[k]; }
  for (int o = 16; o > 0; o >>= 1) s += __shfl_down(s, o, 32);
  const float m = __shfl(s, 0, 32) * (1.f/CD);
  float v = 0.f;
  for (int k = 0; k < 4; k++){ float d = xv[k] - m; v += d*d; }
  for (int o = 16; o > 0; o >>= 1) v += __shfl_down(v, o, 32);
  const float rstd = rsqrtf(__shfl(v, 0, 32) * (1.f/CD) + 1e-5f);
  for (int k = 0; k < 4; k++){
    int c = lane + 32*k;
    qn[t][c] = (xv[k] - m) * rstd * ldT(g1, c) + ldT(b1, c);
  }
  __syncthreads();
  // q = qn @ Wq + bq
  for (int idx = tid; idx < NTOK*CD; idx += 256){
    int tt = idx >> 7, j = idx & 127;
    float acc = ldT(bq, j);
    for (int c = 0; c < CD; c++) acc += qn[tt][c] * ldT(Wq, c*CD + j);
    qq[tt][j] = acc;
  }
  __syncthreads();
  // A (scale 0.25 folded; q.bk constant dropped: softmax-invariant)
  for (int idx = tid; idx < NTOK*NH*CD; idx += 256){
    int tt = idx >> 10, h = (idx >> 7) & 7, c = idx & 127;
    float acc = 0.f;
    for (int d = 0; d < DH; d++) acc += qq[tt][h*DH + d] * ldT(Wk, c*CD + h*DH + d);
    acc *= 0.25f;
    Af[idx] = acc;
    Ab[idx] = __float2bfloat16(acc);
  }
}

// fp32-row x [128x128 bf16 LDS] -> 4 outputs
__device__ __forceinline__ void mat4f(const float* __restrict__ inrow,
                                      const __hip_bfloat16* __restrict__ w_s,
                                      int jb, float a[4]){
  for (int c = 0; c < CD; c++){
    float iv = inrow[c];
    union { uint2 u; __hip_bfloat16 h[4]; } cv;
    cv.u = *(const uint2*)(w_s + (c << 7) + jb);
    a[0] += iv * __bfloat162float(cv.h[0]);
    a[1] += iv * __bfloat162float(cv.h[1]);
    a[2] += iv * __bfloat162float(cv.h[2]);
    a[3] += iv * __bfloat162float(cv.h[3]);
  }
}
__device__ __forceinline__ void mat4b(const __hip_bfloat16* __restrict__ inrow,
                                      const __hip_bfloat16* __restrict__ w_s,
                                      int jb, float a[4]){
  for (int c = 0; c < CD; c++){
    float iv = __bfloat162float(inrow[c]);
    union { uint2 u; __hip_bfloat16 h[4]; } cv;
    cv.u = *(const uint2*)(w_s + (c << 7) + jb);
    a[0] += iv * __bfloat162float(cv.h[0]);
    a[1] += iv * __bfloat162float(cv.h[1]);
    a[2] += iv * __bfloat162float(cv.h[2]);
    a[3] += iv * __bfloat162float(cv.h[3]);
  }
}

// ---------------- fused per-batch kernel (bf16 fast path) ----------------
// LDS arena (64KB), phase-aliased:
//  phase1: A_s bf16 [0,16384) | tgt_s bf16 [16384,30208) | sc f32 [30208,32512)
//  wt bf16 [32768,49152)  (written end of phase1, read phase2)
//  phase2: w_s bf16 [0,32768) | out [49152) x [53248) h2 [57344) f1 [61440) f32 4KB each
__global__ __launch_bounds__(256) void main_bf16(const int* flag,
  const __hip_bfloat16* __restrict__ query, const __hip_bfloat16* __restrict__ tgt,
  const __hip_bfloat16* __restrict__ g2, const __hip_bfloat16* __restrict__ b2,
  const __hip_bfloat16* __restrict__ Wv, const __hip_bfloat16* __restrict__ bv,
  const __hip_bfloat16* __restrict__ Wp, const __hip_bfloat16* __restrict__ bp,
  const __hip_bfloat16* __restrict__ Wf1, const __hip_bfloat16* __restrict__ bf1,
  const __hip_bfloat16* __restrict__ Wf2, const __hip_bfloat16* __restrict__ bf2,
  const __hip_bfloat16* __restrict__ Ab, __hip_bfloat16* __restrict__ outp)
{
  if (*flag != 1) return;
  __shared__ __align__(16) unsigned char arena[65536];
  __hip_bfloat16* A_s   = (__hip_bfloat16*)(arena);
  __hip_bfloat16* tgt_s = (__hip_bfloat16*)(arena + 16384);
  float*          sc    = (float*)(arena + 30208);
  __hip_bfloat16* wt    = (__hip_bfloat16*)(arena + 32768);
  __hip_bfloat16* w_s   = (__hip_bfloat16*)(arena);
  float* out_s = (float*)(arena + 49152);
  float* x_s   = (float*)(arena + 53248);
  float* h2_s  = (float*)(arena + 57344);
  float* f1_s  = (float*)(arena + 61440);

  const int tid = threadIdx.x;
  const int b = blockIdx.x;

  // ---- phase 1a: stage A (16KB) and tgt[b] (13824B) into LDS
  {
    const uint4* src = (const uint4*)Ab;         uint4* dst = (uint4*)A_s;
    for (int i = tid; i < 1024; i += 256) dst[i] = src[i];
    const uint4* s2 = (const uint4*)(tgt + (size_t)b * (LP*CD)); uint4* d2 = (uint4*)tgt_s;
    for (int i = tid; i < 864; i += 256) d2[i] = s2[i];
  }
  __syncthreads();

  // ---- phase 1b: scores  (576 = 8 tok * 9 pos * 8 heads)
  for (int s = tid; s < 576; s += 256){
    int t = s / 72, rem = s % 72, ll = rem >> 3, h = rem & 7;
    int l = pos_of(reg_of(t), ll);
    const __hip_bfloat16* ta = tgt_s + l*CD;
    const __hip_bfloat16* aa = A_s + (t*8 + h)*CD;
    float acc = 0.f;
    for (int c = 0; c < CD; c += 4){
      union { uint2 u; __hip_bfloat16 h[4]; } tv, av;
      tv.u = *(const uint2*)(ta + c);
      av.u = *(const uint2*)(aa + c);
      acc += __bfloat162float(tv.h[0]) * __bfloat162float(av.h[0]);
      acc += __bfloat162float(tv.h[1]) * __bfloat162float(av.h[1]);
      acc += __bfloat162float(tv.h[2]) * __bfloat162float(av.h[2]);
      acc += __bfloat162float(tv.h[3]) * __bfloat162float(av.h[3]);
    }
    sc[(t*8 + h)*9 + ll] = acc;
  }
  __syncthreads();

  // ---- phase 1c: softmax over 9 per (t,h)
  if (tid < 64){
    float* p = sc + tid*9;
    float mx = p[0];
    for (int i = 1; i < 9; i++) mx = fmaxf(mx, p[i]);
    float su = 0.f;
    for (int i = 0; i < 9; i++){ float e = expf(p[i] - mx); p[i] = e; su += e; }
    float inv = 1.f / su;
    for (int i = 0; i < 9; i++) p[i] *= inv;
  }
  __syncthreads();

  // ---- phase 1d: wt[t,h,c] = sum_l a*tgt  (softmax sums to 1 -> bv passes through later)
  for (int idx = tid; idx < 8192; idx += 256){
    int t = idx >> 10, h = (idx >> 7) & 7, c = idx & 127;
    int r = reg_of(t);
    const float* a = sc + (t*8 + h)*9;
    float acc = 0.f;
    for (int ll = 0; ll < 9; ll++)
      acc += a[ll] * __bfloat162float(tgt_s[pos_of(r, ll)*CD + c]);
    wt[idx] = __float2bfloat16(acc);
  }
  __syncthreads();

  // ---- phase 2: four [8x128]@[128x128] matmuls, weights staged in LDS
  const int t2 = tid >> 5, jb = (tid & 31) << 2, hh = jb >> 4;

  { const uint4* s4 = (const uint4*)Wv; uint4* d4 = (uint4*)w_s;
    for (int i = tid; i < 2048; i += 256) d4[i] = s4[i]; }
  __syncthreads();
  { // out = wt @ Wv + bv
    float a[4] = { ldT(bv,jb), ldT(bv,jb+1), ldT(bv,jb+2), ldT(bv,jb+3) };
    mat4b(wt + (t2*8 + hh)*CD, w_s, jb, a);
    out_s[t2*CD+jb] = a[0]; out_s[t2*CD+jb+1] = a[1];
    out_s[t2*CD+jb+2] = a[2]; out_s[t2*CD+jb+3] = a[3];
  }
  __syncthreads();

  { const uint4* s4 = (const uint4*)Wp; uint4* d4 = (uint4*)w_s;
    for (int i = tid; i < 2048; i += 256) d4[i] = s4[i]; }
  __syncthreads();
  { // x = query + out @ Wp + bp   (short_cut is RAW query)
    float a[4] = { ldT(query,t2*CD+jb)   + ldT(bp,jb),
                   ldT(query,t2*CD+jb+1) + ldT(bp,jb+1),
                   ldT(query,t2*CD+jb+2) + ldT(bp,jb+2),
                   ldT(query,t2*CD+jb+3) + ldT(bp,jb+3) };
    mat4f(out_s + t2*CD, w_s, jb, a);
    x_s[t2*CD+jb] = a[0]; x_s[t2*CD+jb+1] = a[1];
    x_s[t2*CD+jb+2] = a[2]; x_s[t2*CD+jb+3] = a[3];
  }
  __syncthreads();

  { // LayerNorm2 rows of x  (32 lanes per token)
    int lane = tid & 31;
    float xv[4]; float s = 0.f;
    for (int k = 0; k < 4; k++){ xv[k] = x_s[t2*CD + lane + 32*k]; s += xv[k]; }
    for (int o = 16; o > 0; o >>= 1) s += __shfl_down(s, o, 32);
    float m = __shfl(s, 0, 32) * (1.f/CD);
    float v = 0.f;
    for (int k = 0; k < 4; k++){ float d = xv[k] - m; v += d*d; }
    for (int o = 16; o > 0; o >>= 1) v += __shfl_down(v, o, 32);
    float rstd = rsqrtf(__shfl(v, 0, 32) * (1.f/CD) + 1e-5f);
    for (int k = 0; k < 4; k++){
      int c = lane + 32*k;
      h2_s[t2*CD + c] = (xv[k] - m) * rstd * ldT(g2, c) + ldT(b2, c);
    }
  }
  { const uint4* s4 = (const uint4*)Wf1; uint4* d4 = (uint4*)w_s;
    for (int i = tid; i < 2048; i += 256) d4[i] = s4[i]; }
  __syncthreads();
  { // f1 = gelu(h2 @ Wf1 + bf1)
    float a[4] = { ldT(bf1,jb), ldT(bf1,jb+1), ldT(bf1,jb+2), ldT(bf1,jb+3) };
    mat4f(h2_s + t2*CD, w_s, jb, a);
    f1_s[t2*CD+jb]   = gelu_exact(a[0]); f1_s[t2*CD+jb+1] = gelu_exact(a[1]);
    f1_s[t2*CD+jb+2] = gelu_exact(a[2]); f1_s[t2*CD+jb+3] = gelu_exact(a[3]);
  }
  __syncthreads();

  { const uint4* s4 = (const uint4*)Wf2; uint4* d4 = (uint4*)w_s;
    for (int i = tid; i < 2048; i += 256) d4[i] = s4[i]; }
  __syncthreads();
  { // y = x + f1 @ Wf2 + bf2
    float a[4] = { ldT(bf2,jb), ldT(bf2,jb+1), ldT(bf2,jb+2), ldT(bf2,jb+3) };
    mat4f(f1_s + t2*CD, w_s, jb, a);
    size_t o = (size_t)b*1024 + t2*CD + jb;
    outp[o]   = __float2bfloat16(x_s[t2*CD+jb]   + a[0]);
    outp[o+1] = __float2bfloat16(x_s[t2*CD+jb+1] + a[1]);
    outp[o+2] = __float2bfloat16(x_s[t2*CD+jb+2] + a[2]);
    outp[o+3] = __float2bfloat16(x_s[t2*CD+jb+3] + a[3]);
  }
}

// ---------------- fp32 fallback (hedge; slow but correct) ----------------
__global__ __launch_bounds__(64) void main_fp32(const int* flag,
  const float* __restrict__ query, const float* __restrict__ tgt,
  const float* __restrict__ g2, const float* __restrict__ b2,
  const float* __restrict__ Wv, const float* __restrict__ bv,
  const float* __restrict__ Wp, const float* __restrict__ bp,
  const float* __restrict__ Wf1, const float* __restrict__ bf1,
  const float* __restrict__ Wf2, const float* __restrict__ bf2,
  const float* __restrict__ Af, float* __restrict__ outp)
{
  if (*flag != 0) return;
  __shared__ float sc2[72];
  __shared__ float wt2[8][128];
  __shared__ float out2[128], x2[128], h22[128], f12[128];
  const int tid = threadIdx.x;
  const int b = blockIdx.x;
  const float* tb = tgt + (size_t)b * (LP*CD);
  for (int t = 0; t < 8; t++){
    int r = reg_of(t);
    for (int s = tid; s < 72; s += 64){
      int ll = s / 8, h = s % 8;
      int l = pos_of(r, ll);
      float acc = 0.f;
      for (int c = 0; c < CD; c++) acc += tb[l*CD + c] * Af[(t*8 + h)*CD + c];
      sc2[h*9 + ll] = acc;
    }
    __syncthreads();
    if (tid < 8){
      float* p = sc2 + tid*9;
      float mx = p[0]; for (int i = 1; i < 9; i++) mx = fmaxf(mx, p[i]);
      float su = 0.f; for (int i = 0; i < 9; i++){ float e = expf(p[i]-mx); p[i] = e; su += e; }
      for (int i = 0; i < 9; i++) p[i] /= su;
    }
    __syncthreads();
    for (int idx = tid; idx < 1024; idx += 64){
      int h = idx >> 7, c = idx & 127;
      float acc = 0.f;
      for (int ll = 0; ll < 9; ll++) acc += sc2[h*9 + ll] * tb[pos_of(r, ll)*CD + c];
      wt2[h][c] = acc;
    }
    __syncthreads();
    for (int j = tid; j < 128; j += 64){
      int h = j >> 4; float acc = bv[j];
      for (int c = 0; c < CD; c++) acc += wt2[h][c] * Wv[c*CD + j];
      out2[j] = acc;
    }
    __syncthreads();
    for (int j = tid; j < 128; j += 64){
      float acc = query[t*CD + j] + bp[j];
      for (int c = 0; c < CD; c++) acc += out2[c] * Wp[c*CD + j];
      x2[j] = acc;
    }
    __syncthreads();
    {
      float s = 0.f; for (int j = tid; j < 128; j += 64) s += x2[j];
      for (int o = 32; o > 0; o >>= 1) s += __shfl_down(s, o, 64);
      float m = __shfl(s, 0, 64) * (1.f/CD);
      float v = 0.f; for (int j = tid; j < 128; j += 64){ float d = x2[j]-m; v += d*d; }
      for (int o = 32; o > 0; o >>= 1) v += __shfl_down(v, o, 64);
      float rstd = rsqrtf(__shfl(v, 0, 64) * (1.f/CD) + 1e-5f);
      for (int j = tid; j < 128; j += 64) h22[j] = (x2[j]-m)*rstd*g2[j] + b2[j];
    }
    __syncthreads();
    for (int j = tid; j < 128; j += 64){
      float acc = bf1[j];
      for (int c = 0; c < CD; c++) acc += h22[c] * Wf1[c*CD + j];
      f12[j] = gelu_exact(acc);
    }
    __syncthreads();
    for (int j = tid; j < 128; j += 64){
      float acc = bf2[j];
      for (int c = 0; c < CD; c++) acc += f12[c] * Wf2[c*CD + j];
      outp[(size_t)b*1024 + t*CD + j] = x2[j] + acc;
    }
    __syncthreads();
  }
}

extern "C" void kernel_launch(void* const* d_in, const int* in_sizes, int n_in,
                              void* d_out, int out_size, void* d_ws, size_t ws_size,
                              hipStream_t stream)
{
  const int B = in_sizes[1] / (LP*CD);   // 8192
  int* flag = (int*)d_ws;
  float* Af = (float*)((char*)d_ws + 64);
  __hip_bfloat16* Ab = (__hip_bfloat16*)((char*)d_ws + 64 + 32768);

  detect_kernel<<<1, 1, 0, stream>>>((const unsigned int*)d_in[2], flag);

  stageA_kernel<__hip_bfloat16, 1><<<1, 256, 0, stream>>>(flag,
      (const __hip_bfloat16*)d_in[0], (const __hip_bfloat16*)d_in[2], (const __hip_bfloat16*)d_in[3],
      (const __hip_bfloat16*)d_in[6], (const __hip_bfloat16*)d_in[7], (const __hip_bfloat16*)d_in[8],
      Af, Ab);
  stageA_kernel<float, 0><<<1, 256, 0, stream>>>(flag,
      (const float*)d_in[0], (const float*)d_in[2], (const float*)d_in[3],
      (const float*)d_in[6], (const float*)d_in[7], (const float*)d_in[8],
      Af, Ab);

  main_bf16<<<B, 256, 0, stream>>>(flag,
      (const __hip_bfloat16*)d_in[0], (const __hip_bfloat16*)d_in[1],
      (const __hip_bfloat16*)d_in[4], (const __hip_bfloat16*)d_in[5],
      (const __hip_bfloat16*)d_in[10], (const __hip_bfloat16*)d_in[11],
      (const __hip_bfloat16*)d_in[12], (const __hip_bfloat16*)d_in[13],
      (const __hip_bfloat16*)d_in[14], (const __hip_bfloat16*)d_in[15],
      (const __hip_bfloat16*)d_in[16], (const __hip_bfloat16*)d_in[17],
      Ab, (__hip_bfloat16*)d_out);

  main_fp32<<<B, 64, 0, stream>>>(flag,
      (const float*)d_in[0], (const float*)d_in[1],
      (const float*)d_in[4], (const float*)d_in[5],
      (const float*)d_in[10], (const float*)d_in[11],
      (const float*)d_in[12], (const float*)d_in[13],
      (const float*)d_in[14], (const float*)d_in[15],
      (const float*)d_in[16], (const float*)d_in[17],
      Af, (float*)d_out);
}

// Round 2
// 1086.383 us; speedup vs baseline: 1.2997x; 1.2997x over previous
//
#include <hip/hip_runtime.h>
#include <stdint.h>

#define CD   128
#define LP   54     // 6*9 positions
#define SROW 132    // padded LDS row stride (floats): float4-aligned, bank-stride 4

__device__ __forceinline__ float gelu_exact(float z){
  return 0.5f * z * (1.0f + erff(z * 0.70710678118654752440f));
}
// region of token t: t0->r0, t1->r1, t>=2 -> t-2
__device__ __forceinline__ int reg_of(int t){ return (t < 2) ? t : (t - 2); }
// position l of region r, local index ll (0..8), grid 6x9
__device__ __forceinline__ int pos_of(int r, int ll){
  return ((r / 3) * 3 + ll / 3) * 9 + (r % 3) * 3 + (ll % 3);
}

// ---------------- stage A (1 block): q = LN(query)@Wq+bq ; A[t,h,c] = 0.25*sum_d q[t,h*16+d]*Wk[c,h*16+d]
// (q.bk term is constant over l -> softmax-invariant -> dropped; K never materialized)
__global__ __launch_bounds__(256) void stageA(
  const float* __restrict__ query, const float* __restrict__ g1, const float* __restrict__ b1,
  const float* __restrict__ Wq, const float* __restrict__ bq, const float* __restrict__ Wk,
  float* __restrict__ Af)
{
  __shared__ float qn[8][CD];
  __shared__ float qq[8][CD];
  const int tid = threadIdx.x;
  const int t = tid >> 5, lane = tid & 31;
  float xv[4]; float s = 0.f;
  for (int k = 0; k < 4; k++){ xv[k] = query[t*CD + lane + 32*k]; s += xv[k]; }
  for (int o = 16; o > 0; o >>= 1) s += __shfl_down(s, o, 32);
  const float m = __shfl(s, 0, 32) * (1.f/CD);
  float v = 0.f;
  for (int k = 0; k < 4; k++){ float d = xv[k] - m; v += d*d; }
  for (int o = 16; o > 0; o >>= 1) v += __shfl_down(v, o, 32);
  const float rstd = rsqrtf(__shfl(v, 0, 32) * (1.f/CD) + 1e-5f);
  for (int k = 0; k < 4; k++){
    int c = lane + 32*k;
    qn[t][c] = (xv[k] - m) * rstd * g1[c] + b1[c];
  }
  __syncthreads();
  for (int idx = tid; idx < 1024; idx += 256){
    int tt = idx >> 7, j = idx & 127;
    float acc = bq[j];
    for (int c = 0; c < CD; c++) acc += qn[tt][c] * Wq[c*CD + j];
    qq[tt][j] = acc;
  }
  __syncthreads();
  for (int idx = tid; idx < 8192; idx += 256){
    int tt = idx >> 10, h = (idx >> 7) & 7, c = idx & 127;
    float acc = 0.f;
    for (int d = 0; d < 16; d++) acc += qq[tt][h*16 + d] * Wk[c*CD + h*16 + d];
    Af[idx] = acc * 0.25f;   // scale (dim/heads)^-0.5 = 0.25 folded
  }
}

// in-row (LDS, float4-aligned) x W[128x128] (global, L1-served) -> 4 columns jb..jb+3
__device__ __forceinline__ void mm4(const float* __restrict__ inrow,
                                    const float* __restrict__ W, int jb, float a[4]){
  #pragma unroll 4
  for (int cq = 0; cq < 32; cq++){
    float4 iv = *(const float4*)(inrow + cq*4);
    float4 w0 = *(const float4*)(W + (cq*4+0)*CD + jb);
    float4 w1 = *(const float4*)(W + (cq*4+1)*CD + jb);
    float4 w2 = *(const float4*)(W + (cq*4+2)*CD + jb);
    float4 w3 = *(const float4*)(W + (cq*4+3)*CD + jb);
    a[0] += iv.x*w0.x + iv.y*w1.x + iv.z*w2.x + iv.w*w3.x;
    a[1] += iv.x*w0.y + iv.y*w1.y + iv.z*w2.y + iv.w*w3.y;
    a[2] += iv.x*w0.z + iv.y*w1.z + iv.z*w2.z + iv.w*w3.z;
    a[3] += iv.x*w0.w + iv.y*w1.w + iv.z*w2.w + iv.w*w3.w;
  }
}

// ---------------- fused per-batch kernel (fp32) ----------------
// LDS arena 64608 B:
//   tgt_s  54x132 f32 [0, 28512)          (dead after wt phase)
//   wt     64x132 f32 [28512, 62304)
//   sc     576 f32    [62304, 64608)
//   row bufs alias [0,16384): out_s@0 x_s@4096 h2_s@8192 f1_s@12288 (8x128 f32 each)
__global__ __launch_bounds__(256, 2) void fused(
  const float* __restrict__ query, const float* __restrict__ tgt,
  const float* __restrict__ g2, const float* __restrict__ b2,
  const float* __restrict__ Wv, const float* __restrict__ bv,
  const float* __restrict__ Wp, const float* __restrict__ bp,
  const float* __restrict__ Wf1, const float* __restrict__ bf1,
  const float* __restrict__ Wf2, const float* __restrict__ bf2,
  const float* __restrict__ Af, float* __restrict__ outp)
{
  __shared__ __align__(16) unsigned char arena[64608];
  float* tgt_s = (float*)(arena);
  float* wt    = (float*)(arena + 28512);
  float* sc    = (float*)(arena + 62304);
  float* out_s = (float*)(arena);
  float* x_s   = (float*)(arena + 4096);
  float* h2_s  = (float*)(arena + 8192);
  float* f1_s  = (float*)(arena + 12288);

  const int tid = threadIdx.x;
  const int b = blockIdx.x;

  // ---- stage tgt[b] into padded LDS (1728 float4)
  {
    const float4* src = (const float4*)(tgt + (size_t)b * (LP*CD));
    for (int i = tid; i < LP*32; i += 256){
      int l = i >> 5, cq = i & 31;
      float4 v = src[i];
      *(float4*)(tgt_s + l*SROW + cq*4) = v;
    }
  }
  __syncthreads();

  // ---- scores: 576 = 8 tok * 9 pos * 8 heads; A from global (L1-resident, all blocks share)
  for (int s = tid; s < 576; s += 256){
    int t = s / 72, rem = s % 72, ll = rem >> 3, h = rem & 7;
    int l = pos_of(reg_of(t), ll);
    const float*  ta = tgt_s + l*SROW;
    const float4* aa = (const float4*)(Af + (t*8 + h)*CD);
    float acc = 0.f;
    #pragma unroll 8
    for (int cq = 0; cq < 32; cq++){
      float4 tv = *(const float4*)(ta + cq*4);
      float4 av = aa[cq];
      acc += tv.x*av.x + tv.y*av.y + tv.z*av.z + tv.w*av.w;
    }
    sc[(t*8 + h)*9 + ll] = acc;
  }
  __syncthreads();

  // ---- softmax over 9 per (t,h)
  if (tid < 64){
    float* p = sc + tid*9;
    float mx = p[0];
    for (int i = 1; i < 9; i++) mx = fmaxf(mx, p[i]);
    float su = 0.f;
    for (int i = 0; i < 9; i++){ float e = __expf(p[i] - mx); p[i] = e; su += e; }
    float inv = 1.f / su;
    for (int i = 0; i < 9; i++) p[i] *= inv;
  }
  __syncthreads();

  // ---- wt[t,h,:] = sum_ll a * tgt_row   (softmax sums to 1 -> bv passes through in Wv matmul)
  for (int idx = tid; idx < 2048; idx += 256){
    int t = idx >> 8, h = (idx >> 5) & 7, cq = idx & 31;
    int r = reg_of(t);
    const float* a = sc + (t*8 + h)*9;
    float4 acc = make_float4(0.f, 0.f, 0.f, 0.f);
    #pragma unroll
    for (int ll = 0; ll < 9; ll++){
      float w = a[ll];
      float4 tv = *(const float4*)(tgt_s + pos_of(r, ll)*SROW + cq*4);
      acc.x += w*tv.x; acc.y += w*tv.y; acc.z += w*tv.z; acc.w += w*tv.w;
    }
    *(float4*)(wt + (t*8 + h)*SROW + cq*4) = acc;
  }
  __syncthreads();   // tgt_s dead from here; row bufs may alias it

  const int t2 = tid >> 5, jb = (tid & 31) << 2, hh = jb >> 4;

  // ---- out = wt @ Wv + bv   (only head-matched wt row feeds column j)
  {
    float a[4] = { bv[jb], bv[jb+1], bv[jb+2], bv[jb+3] };
    mm4(wt + (t2*8 + hh)*SROW, Wv, jb, a);
    *(float4*)(out_s + t2*CD + jb) = make_float4(a[0], a[1], a[2], a[3]);
  }
  __syncthreads();

  // ---- x = query + out @ Wp + bp   (short_cut is RAW query)
  {
    float a[4] = { query[t2*CD+jb]   + bp[jb],
                   query[t2*CD+jb+1] + bp[jb+1],
                   query[t2*CD+jb+2] + bp[jb+2],
                   query[t2*CD+jb+3] + bp[jb+3] };
    mm4(out_s + t2*CD, Wp, jb, a);
    *(float4*)(x_s + t2*CD + jb) = make_float4(a[0], a[1], a[2], a[3]);
  }
  __syncthreads();

  // ---- LayerNorm2 rows of x (32 lanes per token)
  {
    int lane = tid & 31;
    float xv[4]; float s = 0.f;
    for (int k = 0; k < 4; k++){ xv[k] = x_s[t2*CD + lane + 32*k]; s += xv[k]; }
    for (int o = 16; o > 0; o >>= 1) s += __shfl_down(s, o, 32);
    float m = __shfl(s, 0, 32) * (1.f/CD);
    float v = 0.f;
    for (int k = 0; k < 4; k++){ float d = xv[k] - m; v += d*d; }
    for (int o = 16; o > 0; o >>= 1) v += __shfl_down(v, o, 32);
    float rstd = rsqrtf(__shfl(v, 0, 32) * (1.f/CD) + 1e-5f);
    for (int k = 0; k < 4; k++){
      int c = lane + 32*k;
      h2_s[t2*CD + c] = (xv[k] - m) * rstd * g2[c] + b2[c];
    }
  }
  __syncthreads();

  // ---- f1 = gelu(h2 @ Wf1 + bf1)
  {
    float a[4] = { bf1[jb], bf1[jb+1], bf1[jb+2], bf1[jb+3] };
    mm4(h2_s + t2*CD, Wf1, jb, a);
    *(float4*)(f1_s + t2*CD + jb) = make_float4(gelu_exact(a[0]), gelu_exact(a[1]),
                                                gelu_exact(a[2]), gelu_exact(a[3]));
  }
  __syncthreads();

  // ---- y = x + f1 @ Wf2 + bf2
  {
    float a[4] = { bf2[jb], bf2[jb+1], bf2[jb+2], bf2[jb+3] };
    mm4(f1_s + t2*CD, Wf2, jb, a);
    float4 r;
    r.x = x_s[t2*CD+jb]   + a[0];
    r.y = x_s[t2*CD+jb+1] + a[1];
    r.z = x_s[t2*CD+jb+2] + a[2];
    r.w = x_s[t2*CD+jb+3] + a[3];
    *(float4*)(outp + (size_t)b*1024 + t2*CD + jb) = r;
  }
}

extern "C" void kernel_launch(void* const* d_in, const int* in_sizes, int n_in,
                              void* d_out, int out_size, void* d_ws, size_t ws_size,
                              hipStream_t stream)
{
  const int B = in_sizes[1] / (LP*CD);   // 8192
  float* Af = (float*)d_ws;              // 64x128 fp32 = 32 KB

  stageA<<<1, 256, 0, stream>>>(
      (const float*)d_in[0], (const float*)d_in[2], (const float*)d_in[3],
      (const float*)d_in[6], (const float*)d_in[7], (const float*)d_in[8], Af);

  fused<<<B, 256, 0, stream>>>(
      (const float*)d_in[0], (const float*)d_in[1],
      (const float*)d_in[4], (const float*)d_in[5],
      (const float*)d_in[10], (const float*)d_in[11],
      (const float*)d_in[12], (const float*)d_in[13],
      (const float*)d_in[14], (const float*)d_in[15],
      (const float*)d_in[16], (const float*)d_in[17],
      Af, (float*)d_out);
}

// Round 3
// 613.408 us; speedup vs baseline: 2.3019x; 1.7711x over previous
//
#include <hip/hip_runtime.h>
#include <stdint.h>

#define CD 128
#define LP 54
#define SW 136      // LDS row stride in bf16 elements (pad 8 -> 2-way-free banks)
#define G  8        // batches per block

using bfrag = __attribute__((ext_vector_type(8))) short;   // 8 bf16 = 4 VGPR
using f32x4 = __attribute__((ext_vector_type(4))) float;

__device__ __forceinline__ short f2bf(float x){
  union{float f; unsigned u;} v; v.f = x;
  unsigned r = (v.u + 0x7fffu + ((v.u >> 16) & 1u)) >> 16;
  return (short)r;
}
__device__ __forceinline__ float bf2f(short h){
  union{unsigned u; float f;} v; v.u = ((unsigned)(unsigned short)h) << 16;
  return v.f;
}
__device__ __forceinline__ unsigned pack2(float a, float b){
  return (unsigned)(unsigned short)f2bf(a) | ((unsigned)(unsigned short)f2bf(b) << 16);
}
__device__ __forceinline__ float gelu_exact(float z){
  return 0.5f * z * (1.0f + erff(z * 0.70710678118654752440f));
}
__device__ __forceinline__ int reg_of(int t){ return (t < 2) ? t : (t - 2); }
__device__ __forceinline__ int pos_of(int r, int ll){
  return ((r / 3) * 3 + ll / 3) * 9 + (r % 3) * 3 + (ll % 3);
}

// ---------------- stage A (1 block): A[th][c] = 0.25*sum_d (LN(q)@Wq+bq)[t][h*16+d]*Wk[c][h*16+d]
// emitted directly in MFMA B-fragment layout (bf16): slot (kt*4+nt)*64+lane, elem j =
// A[nt*16+(lane&15)][kt*32+(lane>>4)*8+j]
__global__ __launch_bounds__(256) void stageA(
  const float* __restrict__ query, const float* __restrict__ g1, const float* __restrict__ b1,
  const float* __restrict__ Wq, const float* __restrict__ bq, const float* __restrict__ Wk,
  short* __restrict__ Asw)
{
  __shared__ float qn[8][CD];
  __shared__ float qq[8][CD];
  __shared__ float Af[64][CD];
  const int tid = threadIdx.x;
  const int t = tid >> 5, lane = tid & 31;
  float xv[4]; float s = 0.f;
  for (int k = 0; k < 4; k++){ xv[k] = query[t*CD + lane + 32*k]; s += xv[k]; }
  for (int o = 16; o > 0; o >>= 1) s += __shfl_down(s, o, 32);
  const float m = __shfl(s, 0, 32) * (1.f/CD);
  float v = 0.f;
  for (int k = 0; k < 4; k++){ float d = xv[k] - m; v += d*d; }
  for (int o = 16; o > 0; o >>= 1) v += __shfl_down(v, o, 32);
  const float rstd = rsqrtf(__shfl(v, 0, 32) * (1.f/CD) + 1e-5f);
  for (int k = 0; k < 4; k++){
    int c = lane + 32*k;
    qn[t][c] = (xv[k] - m) * rstd * g1[c] + b1[c];
  }
  __syncthreads();
  for (int idx = tid; idx < 1024; idx += 256){
    int tt = idx >> 7, j = idx & 127;
    float acc = bq[j];
    for (int c = 0; c < CD; c++) acc += qn[tt][c] * Wq[c*CD + j];
    qq[tt][j] = acc;
  }
  __syncthreads();
  for (int idx = tid; idx < 8192; idx += 256){
    int tt = idx >> 10, h = (idx >> 7) & 7, c = idx & 127;
    float acc = 0.f;
    for (int d = 0; d < 16; d++) acc += qq[tt][h*16 + d] * Wk[c*CD + h*16 + d];
    Af[tt*8 + h][c] = acc * 0.25f;   // scale (dim/heads)^-0.5 folded; q.bk softmax-invariant, dropped
  }
  __syncthreads();
  for (int sfr = tid; sfr < 1024; sfr += 256){
    int ln = sfr & 63, nt = (sfr >> 6) & 3, kt = sfr >> 8;
    int l15 = ln & 15, qd = ln >> 4;
    bfrag r;
    #pragma unroll
    for (int j = 0; j < 8; j++) r[j] = f2bf(Af[nt*16 + l15][kt*32 + qd*8 + j]);
    ((bfrag*)Asw)[sfr] = r;   // slot == sfr by construction
  }
}

// ---------------- swizzle the 4 weight matrices into B-fragment layout (bf16) ----------------
__global__ __launch_bounds__(256) void swizzleW(
  const float* __restrict__ W0, const float* __restrict__ W1,
  const float* __restrict__ W2, const float* __restrict__ W3,
  short* __restrict__ dst)
{
  const float* W = (blockIdx.x == 0) ? W0 : (blockIdx.x == 1) ? W1 : (blockIdx.x == 2) ? W2 : W3;
  bfrag* out = (bfrag*)dst + (size_t)blockIdx.x * 2048;
  for (int s = threadIdx.x; s < 2048; s += 256){
    int ln = s & 63, nt = (s >> 6) & 7, kt = s >> 9;
    int l15 = ln & 15, qd = ln >> 4;
    bfrag r;
    #pragma unroll
    for (int j = 0; j < 8; j++) r[j] = f2bf(W[(kt*32 + qd*8 + j)*CD + nt*16 + l15]);
    out[s] = r;   // slot == s
  }
}

#define MFMA(a,b,c) __builtin_amdgcn_mfma_f32_16x16x32_bf16((a),(b),(c),0,0,0)

// GEMM helper: acc[2][4] += A_lds[64xCD bf16, stride SW] @ B-frags (this wave: mh m-half, nh n-half)
__device__ __forceinline__ void gemmC(const short* __restrict__ Ab, const bfrag* __restrict__ BF,
                                      int mh, int nh, int l15, int qd, int lane, f32x4 acc[2][4]){
  #pragma unroll
  for (int kt = 0; kt < 4; kt++){
    bfrag a0 = *(const bfrag*)(Ab + ((mh*2+0)*16 + l15)*SW + kt*32 + qd*8);
    bfrag a1 = *(const bfrag*)(Ab + ((mh*2+1)*16 + l15)*SW + kt*32 + qd*8);
    #pragma unroll
    for (int n4 = 0; n4 < 4; n4++){
      bfrag bF = BF[(kt*8 + nh*4 + n4)*64 + lane];
      acc[0][n4] = MFMA(a0, bF, acc[0][n4]);
      acc[1][n4] = MFMA(a1, bF, acc[1][n4]);
    }
  }
}

// ---------------- fused main kernel: G batches per block ----------------
// LDS arena 72704 B: buf0@0 buf1@17408 vp@34816 oall@52224 sc@69632(3072)
// phase C aliases: h2s=buf0, f1s=buf1, LN partials @ sc
__global__ __launch_bounds__(256, 2) void fused(
  const float* __restrict__ query, const float* __restrict__ tgt,
  const float* __restrict__ g2, const float* __restrict__ b2,
  const float* __restrict__ bv, const float* __restrict__ bp,
  const float* __restrict__ bf1, const float* __restrict__ bf2,
  const short* __restrict__ Asw, const short* __restrict__ Wsw,
  float* __restrict__ outp)
{
  __shared__ __align__(16) unsigned char arena[72704];
  short* buf0 = (short*)arena;
  short* buf1 = (short*)(arena + 17408);
  short* vp   = (short*)(arena + 34816);
  short* oall = (short*)(arena + 52224);
  float* sc   = (float*)(arena + 69632);
  short* h2s  = buf0;
  short* f1s  = buf1;
  float* lnS  = sc;          // [64][2] row partial sums  (phase C)
  float* lnQ  = sc + 128;    // [64][2] row partial sq-sums

  const int tid  = threadIdx.x;
  const int lane = tid & 63, wid = tid >> 6;
  const int mh = wid & 1, nh = wid >> 1;
  const int l15 = lane & 15, qd = lane >> 4;
  const int b0 = blockIdx.x * G;

  const bfrag* AF   = (const bfrag*)Asw;
  const bfrag* WvF  = (const bfrag*)Wsw;
  const bfrag* WpF  = (const bfrag*)Wsw + 2048;
  const bfrag* Wf1F = (const bfrag*)Wsw + 4096;
  const bfrag* Wf2F = (const bfrag*)Wsw + 6144;

  // cache Wv fragments in VGPRs (reused across all G batches)
  bfrag bWv[4][4];
  #pragma unroll
  for (int kt = 0; kt < 4; kt++)
    #pragma unroll
    for (int n4 = 0; n4 < 4; n4++)
      bWv[kt][n4] = WvF[(kt*8 + nh*4 + n4)*64 + lane];
  float bvv[4];
  #pragma unroll
  for (int n4 = 0; n4 < 4; n4++) bvv[n4] = bv[(nh*4 + n4)*16 + l15];

  // stage batch 0 (f32 -> bf16)
  {
    const float4* src = (const float4*)(tgt + (size_t)b0 * (LP*CD));
    #pragma unroll
    for (int it = 0; it < 7; it++){
      int i = tid + it*256;
      if (i < LP*32){
        float4 w = src[i];
        uint2 p; p.x = pack2(w.x, w.y); p.y = pack2(w.z, w.w);
        *(uint2*)(buf0 + (i >> 5)*SW + (i & 31)*4) = p;
      }
    }
  }
  __syncthreads();

  for (int g = 0; g < G; g++){
    const short* bufc = (g & 1) ? buf1 : buf0;
    short* bufn = (g & 1) ? buf0 : buf1;

    // prefetch next batch into regs
    float4 pf[7];
    if (g + 1 < G){
      const float4* src = (const float4*)(tgt + (size_t)(b0 + g + 1) * (LP*CD));
      #pragma unroll
      for (int it = 0; it < 7; it++){
        int i = tid + it*256;
        if (i < LP*32) pf[it] = src[i];
      }
    }

    // scores (N=64) + vproj (N=128) MFMA, shared A-frags (tgt rows)
    f32x4 sacc[2][2];
    f32x4 vacc[2][4];
    #pragma unroll
    for (int mt = 0; mt < 2; mt++){
      #pragma unroll
      for (int n2 = 0; n2 < 2; n2++) sacc[mt][n2] = (f32x4){0.f, 0.f, 0.f, 0.f};
      #pragma unroll
      for (int n4 = 0; n4 < 4; n4++) vacc[mt][n4] = (f32x4){bvv[n4], bvv[n4], bvv[n4], bvv[n4]};
    }
    #pragma unroll
    for (int kt = 0; kt < 4; kt++){
      bfrag a0 = *(const bfrag*)(bufc + ((mh*2+0)*16 + l15)*SW + kt*32 + qd*8);
      bfrag a1 = *(const bfrag*)(bufc + ((mh*2+1)*16 + l15)*SW + kt*32 + qd*8);
      bfrag s0 = AF[(kt*4 + nh*2 + 0)*64 + lane];
      bfrag s1 = AF[(kt*4 + nh*2 + 1)*64 + lane];
      sacc[0][0] = MFMA(a0, s0, sacc[0][0]);
      sacc[0][1] = MFMA(a0, s1, sacc[0][1]);
      sacc[1][0] = MFMA(a1, s0, sacc[1][0]);
      sacc[1][1] = MFMA(a1, s1, sacc[1][1]);
      #pragma unroll
      for (int n4 = 0; n4 < 4; n4++){
        vacc[0][n4] = MFMA(a0, bWv[kt][n4], vacc[0][n4]);
        vacc[1][n4] = MFMA(a1, bWv[kt][n4], vacc[1][n4]);
      }
    }

    // store scores (region-filtered -> sc[th][ll]) and vproj (bf16)
    #pragma unroll
    for (int mt = 0; mt < 2; mt++){
      #pragma unroll
      for (int reg = 0; reg < 4; reg++){
        int l = (mh*2 + mt)*16 + qd*4 + reg;
        if (l < LP){
          int hr = l / 9, wc = l - hr*9;
          int hq = hr / 3, wq = wc / 3;
          int rl = hq*3 + wq;
          int ll = (hr - hq*3)*3 + (wc - wq*3);
          #pragma unroll
          for (int n2 = 0; n2 < 2; n2++){
            int th = (nh*2 + n2)*16 + l15;
            int t  = th >> 3;
            int rt = (t < 2) ? t : (t - 2);
            if (rl == rt) sc[th*12 + ll] = sacc[mt][n2][reg];
          }
        }
        int row = (mh*2 + mt)*16 + qd*4 + reg;
        #pragma unroll
        for (int n4 = 0; n4 < 4; n4++){
          int col = (nh*4 + n4)*16 + l15;
          vp[row*SW + col] = f2bf(vacc[mt][n4][reg]);
        }
      }
    }
    __syncthreads();

    // softmax over 9 per (t,h); concurrently write next batch staging
    if (tid < 64){
      float* p = sc + tid*12;
      float mx = p[0];
      #pragma unroll
      for (int i = 1; i < 9; i++) mx = fmaxf(mx, p[i]);
      float su = 0.f;
      #pragma unroll
      for (int i = 0; i < 9; i++){ float e = __expf(p[i] - mx); p[i] = e; su += e; }
      float inv = 1.f / su;
      #pragma unroll
      for (int i = 0; i < 9; i++) p[i] *= inv;
    }
    if (g + 1 < G){
      #pragma unroll
      for (int it = 0; it < 7; it++){
        int i = tid + it*256;
        if (i < LP*32){
          uint2 p; p.x = pack2(pf[it].x, pf[it].y); p.y = pack2(pf[it].z, pf[it].w);
          *(uint2*)(bufn + (i >> 5)*SW + (i & 31)*4) = p;
        }
      }
    }
    __syncthreads();

    // fold: out_att[t][j] = sum_ll a[t,h(j),ll] * vproj[pos][j]  -> oall row g*8+t (bf16)
    #pragma unroll
    for (int it = 0; it < 4; it++){
      int idx = tid + it*256;
      int t = idx >> 7, j = idx & 127;
      int th = t*8 + (j >> 4);
      int rt = reg_of(t);
      float a = 0.f;
      #pragma unroll
      for (int ll = 0; ll < 9; ll++)
        a += sc[th*12 + ll] * bf2f(vp[pos_of(rt, ll)*SW + j]);
      oall[(g*8 + t)*SW + j] = f2bf(a);
    }
    __syncthreads();
  }

  // ================= phase C: rows m = g*8+t (M=64) =================
  // x = query_row + oall @ Wp + bp    (x kept f32 in registers)
  f32x4 xacc[2][4];
  #pragma unroll
  for (int n4 = 0; n4 < 4; n4++){
    int col = (nh*4 + n4)*16 + l15;
    float bpv = bp[col];
    #pragma unroll
    for (int reg = 0; reg < 4; reg++){
      int t = (qd*4 + reg) & 7;
      float val = bpv + query[t*CD + col];
      xacc[0][n4][reg] = val;
      xacc[1][n4][reg] = val;
    }
  }
  gemmC(oall, WpF, mh, nh, l15, qd, lane, xacc);

  // LayerNorm over rows (cross-wave partials via LDS)
  #pragma unroll
  for (int mt = 0; mt < 2; mt++){
    #pragma unroll
    for (int reg = 0; reg < 4; reg++){
      float x0 = xacc[mt][0][reg], x1 = xacc[mt][1][reg], x2 = xacc[mt][2][reg], x3 = xacc[mt][3][reg];
      float p  = x0 + x1 + x2 + x3;
      float p2 = x0*x0 + x1*x1 + x2*x2 + x3*x3;
      #pragma unroll
      for (int msk = 1; msk < 16; msk <<= 1){
        p  += __shfl_xor(p,  msk);
        p2 += __shfl_xor(p2, msk);
      }
      if (l15 == 0){
        int row = (mh*2 + mt)*16 + qd*4 + reg;
        lnS[row*2 + nh] = p;
        lnQ[row*2 + nh] = p2;
      }
    }
  }
  __syncthreads();
  {
    float g2v[4], b2v[4];
    #pragma unroll
    for (int n4 = 0; n4 < 4; n4++){
      int col = (nh*4 + n4)*16 + l15;
      g2v[n4] = g2[col]; b2v[n4] = b2[col];
    }
    #pragma unroll
    for (int mt = 0; mt < 2; mt++){
      #pragma unroll
      for (int reg = 0; reg < 4; reg++){
        int row = (mh*2 + mt)*16 + qd*4 + reg;
        float su = lnS[row*2] + lnS[row*2 + 1];
        float sq = lnQ[row*2] + lnQ[row*2 + 1];
        float mu = su * (1.f/CD);
        float var = sq * (1.f/CD) - mu*mu;
        float rs = rsqrtf(var + 1e-5f);
        #pragma unroll
        for (int n4 = 0; n4 < 4; n4++){
          int col = (nh*4 + n4)*16 + l15;
          float hv = (xacc[mt][n4][reg] - mu) * rs * g2v[n4] + b2v[n4];
          h2s[row*SW + col] = f2bf(hv);
        }
      }
    }
  }
  __syncthreads();

  // f1 = gelu(h2 @ Wf1 + bf1)
  f32x4 facc[2][4];
  #pragma unroll
  for (int n4 = 0; n4 < 4; n4++){
    int col = (nh*4 + n4)*16 + l15;
    float bv1 = bf1[col];
    #pragma unroll
    for (int reg = 0; reg < 4; reg++){ facc[0][n4][reg] = bv1; facc[1][n4][reg] = bv1; }
  }
  gemmC(h2s, Wf1F, mh, nh, l15, qd, lane, facc);
  #pragma unroll
  for (int mt = 0; mt < 2; mt++)
    #pragma unroll
    for (int reg = 0; reg < 4; reg++){
      int row = (mh*2 + mt)*16 + qd*4 + reg;
      #pragma unroll
      for (int n4 = 0; n4 < 4; n4++){
        int col = (nh*4 + n4)*16 + l15;
        f1s[row*SW + col] = f2bf(gelu_exact(facc[mt][n4][reg]));
      }
    }
  __syncthreads();

  // y = x + f1 @ Wf2 + bf2
  f32x4 yacc[2][4];
  #pragma unroll
  for (int n4 = 0; n4 < 4; n4++){
    int col = (nh*4 + n4)*16 + l15;
    float bv2 = bf2[col];
    #pragma unroll
    for (int reg = 0; reg < 4; reg++){ yacc[0][n4][reg] = bv2; yacc[1][n4][reg] = bv2; }
  }
  gemmC(f1s, Wf2F, mh, nh, l15, qd, lane, yacc);

  const size_t obase = (size_t)blockIdx.x * (G*8*CD);
  #pragma unroll
  for (int mt = 0; mt < 2; mt++)
    #pragma unroll
    for (int reg = 0; reg < 4; reg++){
      int row = (mh*2 + mt)*16 + qd*4 + reg;
      #pragma unroll
      for (int n4 = 0; n4 < 4; n4++){
        int col = (nh*4 + n4)*16 + l15;
        outp[obase + row*CD + col] = xacc[mt][n4][reg] + yacc[mt][n4][reg];
      }
    }
}

extern "C" void kernel_launch(void* const* d_in, const int* in_sizes, int n_in,
                              void* d_out, int out_size, void* d_ws, size_t ws_size,
                              hipStream_t stream)
{
  const int B = in_sizes[1] / (LP*CD);   // 8192
  short* Asw = (short*)d_ws;                              // 16 KB
  short* Wsw = (short*)((char*)d_ws + 16384);             // 4 x 32 KB

  stageA<<<1, 256, 0, stream>>>(
      (const float*)d_in[0], (const float*)d_in[2], (const float*)d_in[3],
      (const float*)d_in[6], (const float*)d_in[7], (const float*)d_in[8], Asw);

  swizzleW<<<4, 256, 0, stream>>>(
      (const float*)d_in[10], (const float*)d_in[12],
      (const float*)d_in[14], (const float*)d_in[16], Wsw);

  fused<<<B / G, 256, 0, stream>>>(
      (const float*)d_in[0], (const float*)d_in[1],
      (const float*)d_in[4], (const float*)d_in[5],
      (const float*)d_in[11], (const float*)d_in[13],
      (const float*)d_in[15], (const float*)d_in[17],
      Asw, Wsw, (float*)d_out);
}